// Round 1
// baseline (11149.582 us; speedup 1.0000x reference)
//
#include <hip/hip_runtime.h>
#include <hip/hip_bf16.h>

#define N_NODES 100000
#define N_EDGES 3200000
#define D 256            // D_IN == D_OUT == 256
#define GEMM_ROWS 16     // rows of X per block (100000 % 16 == 0)

// -------- GEMM: support[N,256] = X[N,256] @ W[256,256] (fp32 vector ALU) ----
// Block = 256 threads = 4 waves. Wave w handles rows row0..row0+3.
// Lane l handles columns 4l..4l+3 (float4). 16 fp32 acc per thread.
__global__ __launch_bounds__(256) void gemm_kernel(
    const float* __restrict__ X, const float* __restrict__ W,
    float* __restrict__ S)
{
    const int lane = threadIdx.x & 63;
    const int rgrp = threadIdx.x >> 6;              // 0..3 (wave id)
    const int row0 = blockIdx.x * GEMM_ROWS + rgrp * 4;

    const float4* __restrict__ W4 = (const float4*)W;   // W[k][c] row-major
    const float4* __restrict__ X4 = (const float4*)X;

    float4 acc[4];
    #pragma unroll
    for (int i = 0; i < 4; ++i) acc[i] = make_float4(0.f, 0.f, 0.f, 0.f);

    for (int k4 = 0; k4 < D / 4; ++k4) {
        float4 w0 = W4[(size_t)(k4 * 4 + 0) * 64 + lane];
        float4 w1 = W4[(size_t)(k4 * 4 + 1) * 64 + lane];
        float4 w2 = W4[(size_t)(k4 * 4 + 2) * 64 + lane];
        float4 w3 = W4[(size_t)(k4 * 4 + 3) * 64 + lane];
        #pragma unroll
        for (int i = 0; i < 4; ++i) {
            float4 x = X4[(size_t)(row0 + i) * 64 + k4];
            acc[i].x += x.x * w0.x + x.y * w1.x + x.z * w2.x + x.w * w3.x;
            acc[i].y += x.x * w0.y + x.y * w1.y + x.z * w2.y + x.w * w3.y;
            acc[i].z += x.x * w0.z + x.y * w1.z + x.z * w2.z + x.w * w3.z;
            acc[i].w += x.x * w0.w + x.y * w1.w + x.z * w2.w + x.w * w3.w;
        }
    }

    float4* __restrict__ S4 = (float4*)S;
    #pragma unroll
    for (int i = 0; i < 4; ++i)
        S4[(size_t)(row0 + i) * 64 + lane] = acc[i];
}

// -------- init: out[n][d] = bias[d] ----------------------------------------
__global__ __launch_bounds__(256) void init_out_kernel(
    float* __restrict__ out, const float* __restrict__ bias)
{
    const size_t i = (size_t)blockIdx.x * blockDim.x + threadIdx.x; // float4 idx
    const float4 b = ((const float4*)bias)[i & 63];
    ((float4*)out)[i] = b;
}

// -------- scatter: out[row[e]] += val[e] * support[col[e]] -----------------
// One wave per edge; lane l handles float4 at column 4l.
__global__ __launch_bounds__(256) void scatter_kernel(
    const float* __restrict__ S, const int* __restrict__ row,
    const int* __restrict__ col, const float* __restrict__ val,
    float* __restrict__ out)
{
    const int e = blockIdx.x * 4 + (threadIdx.x >> 6);
    const int lane = threadIdx.x & 63;
    const int r = row[e];
    const int c = col[e];
    const float v = val[e];

    const float4 s = ((const float4*)(S + (size_t)c * D))[lane];
    float* o = out + (size_t)r * D + lane * 4;
    atomicAdd(o + 0, s.x * v);
    atomicAdd(o + 1, s.y * v);
    atomicAdd(o + 2, s.z * v);
    atomicAdd(o + 3, s.w * v);
}

extern "C" void kernel_launch(void* const* d_in, const int* in_sizes, int n_in,
                              void* d_out, int out_size, void* d_ws, size_t ws_size,
                              hipStream_t stream) {
    const float* X    = (const float*)d_in[0];
    const int*   row  = (const int*)d_in[1];
    const int*   col  = (const int*)d_in[2];
    const float* val  = (const float*)d_in[3];
    const float* W    = (const float*)d_in[4];
    const float* bias = (const float*)d_in[5];
    float* out = (float*)d_out;
    float* S   = (float*)d_ws;   // support: N_NODES * D * 4 = 97.7 MiB

    // 1) support = X @ W
    gemm_kernel<<<N_NODES / GEMM_ROWS, 256, 0, stream>>>(X, W, S);

    // 2) out = bias (broadcast)
    const size_t total4 = (size_t)N_NODES * (D / 4);        // 6.4M float4
    init_out_kernel<<<(int)(total4 / 256), 256, 0, stream>>>(out, bias);

    // 3) scatter-add edges
    scatter_kernel<<<N_EDGES / 4, 256, 0, stream>>>(S, row, col, val, out);
}

// Round 2
// 1415.415 us; speedup vs baseline: 7.8773x; 7.8773x over previous
//
#include <hip/hip_runtime.h>

#define N_NODES 100000
#define N_EDGES 3200000
#define D 256            // D_IN == D_OUT == 256
#define GEMM_ROWS 16     // rows of X per block (100000 % 16 == 0)

using u16 = unsigned short;
using u32 = unsigned int;

// bf16 <-> f32 (RNE, matches v_cvt; NaN ignored — inputs are finite)
__device__ inline u16 f2bf(float f) {
    u32 x = __builtin_bit_cast(u32, f);
    return (u16)((x + 0x7FFFu + ((x >> 16) & 1u)) >> 16);
}
__device__ inline float bf2f(u16 u) {
    return __builtin_bit_cast(float, (u32)u << 16);
}

// -------- GEMM: S[N,256] = X[N,256] @ W[256,256], fp32 acc, bf16 store -----
__global__ __launch_bounds__(256) void gemm_kernel(
    const float* __restrict__ X, const float* __restrict__ W,
    u16* __restrict__ S)
{
    const int lane = threadIdx.x & 63;
    const int rgrp = threadIdx.x >> 6;              // wave id 0..3
    const int row0 = blockIdx.x * GEMM_ROWS + rgrp * 4;

    const float4* __restrict__ W4 = (const float4*)W;   // W[k][c] row-major
    const float4* __restrict__ X4 = (const float4*)X;

    float4 acc[4];
    #pragma unroll
    for (int i = 0; i < 4; ++i) acc[i] = make_float4(0.f, 0.f, 0.f, 0.f);

    for (int k4 = 0; k4 < D / 4; ++k4) {
        float4 w0 = W4[(size_t)(k4 * 4 + 0) * 64 + lane];
        float4 w1 = W4[(size_t)(k4 * 4 + 1) * 64 + lane];
        float4 w2 = W4[(size_t)(k4 * 4 + 2) * 64 + lane];
        float4 w3 = W4[(size_t)(k4 * 4 + 3) * 64 + lane];
        #pragma unroll
        for (int i = 0; i < 4; ++i) {
            float4 x = X4[(size_t)(row0 + i) * 64 + k4];
            acc[i].x += x.x * w0.x + x.y * w1.x + x.z * w2.x + x.w * w3.x;
            acc[i].y += x.x * w0.y + x.y * w1.y + x.z * w2.y + x.w * w3.y;
            acc[i].z += x.x * w0.z + x.y * w1.z + x.z * w2.z + x.w * w3.z;
            acc[i].w += x.x * w0.w + x.y * w1.w + x.z * w2.w + x.w * w3.w;
        }
    }

    ushort4* __restrict__ S4 = (ushort4*)S;
    #pragma unroll
    for (int i = 0; i < 4; ++i) {
        ushort4 p;
        p.x = f2bf(acc[i].x); p.y = f2bf(acc[i].y);
        p.z = f2bf(acc[i].z); p.w = f2bf(acc[i].w);
        S4[(size_t)(row0 + i) * 64 + lane] = p;
    }
}

// -------- zero the histogram (ws is poisoned 0xAA before every call) -------
__global__ __launch_bounds__(256) void zero_kernel(int* __restrict__ p, int n) {
    const int i = blockIdx.x * 256 + threadIdx.x;
    if (i < n) p[i] = 0;
}

// -------- histogram: cnt[r] = #edges with row==r ---------------------------
__global__ __launch_bounds__(256) void hist_kernel(
    const int* __restrict__ row, int* __restrict__ cnt)
{
    const int e = blockIdx.x * 256 + threadIdx.x;
    atomicAdd(&cnt[row[e]], 1);
}

// -------- single-block exclusive scan: cnt -> starts (and cnt := excl) -----
__global__ __launch_bounds__(1024) void scan_kernel(
    int* __restrict__ cnt, int* __restrict__ starts)
{
    __shared__ int wsum[16];
    __shared__ int carry;
    const int tid = threadIdx.x;
    const int lane = tid & 63;
    const int wv = tid >> 6;
    if (tid == 0) carry = 0;
    __syncthreads();
    for (int base = 0; base < N_NODES; base += 1024) {
        const int i = base + tid;
        const int c = (i < N_NODES) ? cnt[i] : 0;
        int x = c;
        #pragma unroll
        for (int off = 1; off < 64; off <<= 1) {
            int y = __shfl_up(x, off);
            if (lane >= off) x += y;
        }
        if (lane == 63) wsum[wv] = x;
        __syncthreads();
        if (tid == 0) {
            int run = carry;
            #pragma unroll
            for (int w = 0; w < 16; ++w) { int t = wsum[w]; wsum[w] = run; run += t; }
            carry = run;
        }
        __syncthreads();
        const int excl = x - c + wsum[wv];
        if (i < N_NODES) { starts[i] = excl; cnt[i] = excl; }
        __syncthreads();
    }
    if (tid == 0) starts[N_NODES] = carry;   // == N_EDGES
}

// -------- placement: perm holds edge ids grouped by row --------------------
__global__ __launch_bounds__(256) void place_kernel(
    const int* __restrict__ row, int* __restrict__ cursor, int* __restrict__ perm)
{
    const int e = blockIdx.x * 256 + threadIdx.x;
    const int r = row[e];
    const int pos = atomicAdd(&cursor[r], 1);
    perm[pos] = e;
}

// -------- segmented reduce: one wave per output row, no atomics ------------
__global__ __launch_bounds__(256) void reduce_kernel(
    const u16* __restrict__ S, const int* __restrict__ starts,
    const int* __restrict__ perm, const int* __restrict__ col,
    const float* __restrict__ val, const float* __restrict__ bias,
    float* __restrict__ out)
{
    const int lane = threadIdx.x & 63;
    const int r = blockIdx.x * 4 + (threadIdx.x >> 6);
    const int s0 = starts[r];
    const int s1 = starts[r + 1];

    const ushort4* __restrict__ S4 = (const ushort4*)S;
    float4 acc = make_float4(0.f, 0.f, 0.f, 0.f);

    int j = s0;
    for (; j + 1 < s1; j += 2) {          // 2 edges in flight per iteration
        const int e0 = perm[j], e1 = perm[j + 1];
        const int c0 = col[e0], c1 = col[e1];
        const float v0 = val[e0], v1 = val[e1];
        const ushort4 a = S4[(size_t)c0 * 64 + lane];
        const ushort4 b = S4[(size_t)c1 * 64 + lane];
        acc.x += v0 * bf2f(a.x) + v1 * bf2f(b.x);
        acc.y += v0 * bf2f(a.y) + v1 * bf2f(b.y);
        acc.z += v0 * bf2f(a.z) + v1 * bf2f(b.z);
        acc.w += v0 * bf2f(a.w) + v1 * bf2f(b.w);
    }
    if (j < s1) {
        const int e0 = perm[j];
        const int c0 = col[e0];
        const float v0 = val[e0];
        const ushort4 a = S4[(size_t)c0 * 64 + lane];
        acc.x += v0 * bf2f(a.x);
        acc.y += v0 * bf2f(a.y);
        acc.z += v0 * bf2f(a.z);
        acc.w += v0 * bf2f(a.w);
    }

    const float4 b4 = ((const float4*)bias)[lane];
    acc.x += b4.x; acc.y += b4.y; acc.z += b4.z; acc.w += b4.w;
    ((float4*)out)[(size_t)r * 64 + lane] = acc;
}

extern "C" void kernel_launch(void* const* d_in, const int* in_sizes, int n_in,
                              void* d_out, int out_size, void* d_ws, size_t ws_size,
                              hipStream_t stream) {
    const float* X    = (const float*)d_in[0];
    const int*   row  = (const int*)d_in[1];
    const int*   col  = (const int*)d_in[2];
    const float* val  = (const float*)d_in[3];
    const float* W    = (const float*)d_in[4];
    const float* bias = (const float*)d_in[5];
    float* out = (float*)d_out;

    // workspace layout (64.8 MB total; 97.7 MB proven available in round 1)
    char* ws = (char*)d_ws;
    u16* S      = (u16*)ws;                                   // 51,200,000 B
    int* starts = (int*)(ws + 51200000);                      //    400,016 B (N+1 ints, padded)
    int* cnt    = (int*)(ws + 51200000 + 400016);             //    400,000 B
    int* perm   = (int*)(ws + 51200000 + 400016 + 400000);    // 12,800,000 B

    // 1) support = X @ W  (bf16 store)
    gemm_kernel<<<N_NODES / GEMM_ROWS, 256, 0, stream>>>(X, W, S);

    // 2) CSR build: histogram -> scan -> placement
    zero_kernel<<<(N_NODES + 255) / 256, 256, 0, stream>>>(cnt, N_NODES);
    hist_kernel<<<N_EDGES / 256, 256, 0, stream>>>(row, cnt);
    scan_kernel<<<1, 1024, 0, stream>>>(cnt, starts);
    place_kernel<<<N_EDGES / 256, 256, 0, stream>>>(row, cnt, perm);

    // 3) segmented reduce, one wave per row, single write per output element
    reduce_kernel<<<N_NODES / 4, 256, 0, stream>>>(S, starts, perm, col, val, bias, out);
}

// Round 3
// 1035.719 us; speedup vs baseline: 10.7651x; 1.3666x over previous
//
#include <hip/hip_runtime.h>

#define N_NODES 100000
#define N_EDGES 3200000
#define D 256
#define N_TILES (N_NODES / 16)          // 6250 row-tiles of 16
#define NBLK ((N_NODES + 255) / 256)    // 391 scan blocks

using u16 = unsigned short;
using u32 = unsigned int;

typedef __attribute__((ext_vector_type(8))) short bf16x8;
typedef __attribute__((ext_vector_type(4))) float f32x4;

__device__ inline u16 f2bf(float f) {
    u32 x = __builtin_bit_cast(u32, f);
    return (u16)((x + 0x7FFFu + ((x >> 16) & 1u)) >> 16);
}
__device__ inline float bf2f(u16 u) {
    return __builtin_bit_cast(float, (u32)u << 16);
}

// -------- prep: shuffle W into B-fragment layout ---------------------------
// Wf[nt(16)][kt(8)][lane(64)][j(8)]: b[j] = W[kt*32 + (lane>>4)*8 + j][nt*16 + (lane&15)]
__global__ __launch_bounds__(256) void wshuffle_kernel(
    const float* __restrict__ W, u16* __restrict__ Wf)
{
    const int t = blockIdx.x * 256 + threadIdx.x;   // 0..8191
    const int nt = t >> 9;
    const int kt = (t >> 6) & 7;
    const int lane = t & 63;
    const int kbase = kt * 32 + (lane >> 4) * 8;
    const int n = nt * 16 + (lane & 15);
    u16 frag[8];
    #pragma unroll
    for (int j = 0; j < 8; ++j)
        frag[j] = f2bf(W[(size_t)(kbase + j) * D + n]);
    #pragma unroll
    for (int j = 0; j < 8; ++j)
        Wf[(size_t)t * 8 + j] = frag[j];
}

// -------- GEMM: S[N,256](bf16) = X @ W via mfma_f32_16x16x32_bf16 ----------
// One wave per 16-row tile; 16 accumulators (16x16 tiles) cover all 256 cols.
__global__ __launch_bounds__(256) void gemm_mfma_kernel(
    const float* __restrict__ X, const u16* __restrict__ Wf,
    u16* __restrict__ S)
{
    const int lane = threadIdx.x & 63;
    const int tile = blockIdx.x * 4 + (threadIdx.x >> 6);
    if (tile >= N_TILES) return;
    const int row0 = tile * 16;
    const int m = lane & 15;
    const int quad = lane >> 4;

    f32x4 acc[16];
    #pragma unroll
    for (int t = 0; t < 16; ++t) acc[t] = (f32x4){0.f, 0.f, 0.f, 0.f};

    const float* xrow = X + (size_t)(row0 + m) * D + quad * 8;
    const bf16x8* __restrict__ Bf = (const bf16x8*)Wf;

    for (int k0 = 0; k0 < 8; ++k0) {                 // K-step = 32
        const float4 xa = *(const float4*)(xrow + k0 * 32);
        const float4 xb = *(const float4*)(xrow + k0 * 32 + 4);
        bf16x8 a;
        a[0] = (short)f2bf(xa.x); a[1] = (short)f2bf(xa.y);
        a[2] = (short)f2bf(xa.z); a[3] = (short)f2bf(xa.w);
        a[4] = (short)f2bf(xb.x); a[5] = (short)f2bf(xb.y);
        a[6] = (short)f2bf(xb.z); a[7] = (short)f2bf(xb.w);
        #pragma unroll
        for (int nt = 0; nt < 16; ++nt) {
            const bf16x8 b = Bf[(size_t)nt * 8 * 64 + k0 * 64 + lane];
            acc[nt] = __builtin_amdgcn_mfma_f32_16x16x32_bf16(a, b, acc[nt], 0, 0, 0);
        }
    }

    // C/D layout: col = lane&15, row = quad*4 + i
    #pragma unroll
    for (int nt = 0; nt < 16; ++nt) {
        #pragma unroll
        for (int i = 0; i < 4; ++i)
            S[(size_t)(row0 + quad * 4 + i) * D + nt * 16 + m] = f2bf(acc[nt][i]);
    }
}

// -------- zero the histogram ----------------------------------------------
__global__ __launch_bounds__(256) void zero_kernel(int* __restrict__ p, int n) {
    const int i = blockIdx.x * 256 + threadIdx.x;
    if (i < n) p[i] = 0;
}

// -------- histogram --------------------------------------------------------
__global__ __launch_bounds__(256) void hist_kernel(
    const int* __restrict__ row, int* __restrict__ cnt)
{
    const int e = blockIdx.x * 256 + threadIdx.x;
    atomicAdd(&cnt[row[e]], 1);
}

// -------- hierarchical scan (3 kernels) ------------------------------------
__global__ __launch_bounds__(256) void blocksum_kernel(
    const int* __restrict__ cnt, int* __restrict__ bsum)
{
    __shared__ int sh[4];
    const int i = blockIdx.x * 256 + threadIdx.x;
    int x = (i < N_NODES) ? cnt[i] : 0;
    #pragma unroll
    for (int off = 32; off > 0; off >>= 1) x += __shfl_xor(x, off);
    if ((threadIdx.x & 63) == 0) sh[threadIdx.x >> 6] = x;
    __syncthreads();
    if (threadIdx.x == 0) bsum[blockIdx.x] = sh[0] + sh[1] + sh[2] + sh[3];
}

__global__ __launch_bounds__(512) void bscan_kernel(
    const int* __restrict__ bsum, int* __restrict__ boff, int* __restrict__ starts)
{
    __shared__ int wsum[8];
    const int tid = threadIdx.x, lane = tid & 63, wv = tid >> 6;
    const int c = (tid < NBLK) ? bsum[tid] : 0;
    int x = c;
    #pragma unroll
    for (int off = 1; off < 64; off <<= 1) {
        int y = __shfl_up(x, off);
        if (lane >= off) x += y;
    }
    if (lane == 63) wsum[wv] = x;
    __syncthreads();
    if (tid == 0) {
        int run = 0;
        #pragma unroll
        for (int w = 0; w < 8; ++w) { int t = wsum[w]; wsum[w] = run; run += t; }
        starts[N_NODES] = N_EDGES;
    }
    __syncthreads();
    if (tid < NBLK) boff[tid] = x - c + wsum[wv];
}

__global__ __launch_bounds__(256) void localscan_kernel(
    int* __restrict__ cnt, const int* __restrict__ boff, int* __restrict__ starts)
{
    __shared__ int wsum[4];
    const int tid = threadIdx.x, lane = tid & 63, wv = tid >> 6;
    const int i = blockIdx.x * 256 + tid;
    const int c = (i < N_NODES) ? cnt[i] : 0;
    int x = c;
    #pragma unroll
    for (int off = 1; off < 64; off <<= 1) {
        int y = __shfl_up(x, off);
        if (lane >= off) x += y;
    }
    if (lane == 63) wsum[wv] = x;
    __syncthreads();
    if (tid == 0) {
        int run = 0;
        #pragma unroll
        for (int w = 0; w < 4; ++w) { int t = wsum[w]; wsum[w] = run; run += t; }
    }
    __syncthreads();
    const int excl = x - c + wsum[wv] + boff[blockIdx.x];
    if (i < N_NODES) { starts[i] = excl; cnt[i] = excl; }
}

// -------- placement --------------------------------------------------------
__global__ __launch_bounds__(256) void place_kernel(
    const int* __restrict__ row, int* __restrict__ cursor, int* __restrict__ perm)
{
    const int e = blockIdx.x * 256 + threadIdx.x;
    const int r = row[e];
    const int pos = atomicAdd(&cursor[r], 1);
    perm[pos] = e;
}

// -------- segmented reduce: one wave/row, cooperative metadata load --------
__global__ __launch_bounds__(256) void reduce_kernel(
    const u16* __restrict__ S, const int* __restrict__ starts,
    const int* __restrict__ perm, const int* __restrict__ col,
    const float* __restrict__ val, const float* __restrict__ bias,
    float* __restrict__ out)
{
    const int lane = threadIdx.x & 63;
    const int r = blockIdx.x * 4 + (threadIdx.x >> 6);
    const int s0 = starts[r];
    const int s1 = starts[r + 1];

    const ushort4* __restrict__ S4 = (const ushort4*)S;
    float4 acc = make_float4(0.f, 0.f, 0.f, 0.f);

    for (int base = s0; base < s1; base += 64) {
        const int n = min(64, s1 - base);
        int c = 0; float v = 0.f;
        if (lane < n) {
            const int e = perm[base + lane];
            c = col[e];
            v = val[e];
        }
        int i = 0;
        for (; i + 3 < n; i += 4) {
            const int c0 = __shfl(c, i),     c1 = __shfl(c, i + 1);
            const int c2 = __shfl(c, i + 2), c3 = __shfl(c, i + 3);
            const float v0 = __shfl(v, i),     v1 = __shfl(v, i + 1);
            const float v2 = __shfl(v, i + 2), v3 = __shfl(v, i + 3);
            const ushort4 a0 = S4[(size_t)c0 * 64 + lane];
            const ushort4 a1 = S4[(size_t)c1 * 64 + lane];
            const ushort4 a2 = S4[(size_t)c2 * 64 + lane];
            const ushort4 a3 = S4[(size_t)c3 * 64 + lane];
            acc.x += v0 * bf2f(a0.x) + v1 * bf2f(a1.x) + v2 * bf2f(a2.x) + v3 * bf2f(a3.x);
            acc.y += v0 * bf2f(a0.y) + v1 * bf2f(a1.y) + v2 * bf2f(a2.y) + v3 * bf2f(a3.y);
            acc.z += v0 * bf2f(a0.z) + v1 * bf2f(a1.z) + v2 * bf2f(a2.z) + v3 * bf2f(a3.z);
            acc.w += v0 * bf2f(a0.w) + v1 * bf2f(a1.w) + v2 * bf2f(a2.w) + v3 * bf2f(a3.w);
        }
        for (; i < n; ++i) {
            const int c0 = __shfl(c, i);
            const float v0 = __shfl(v, i);
            const ushort4 a0 = S4[(size_t)c0 * 64 + lane];
            acc.x += v0 * bf2f(a0.x);
            acc.y += v0 * bf2f(a0.y);
            acc.z += v0 * bf2f(a0.z);
            acc.w += v0 * bf2f(a0.w);
        }
    }

    const float4 b4 = ((const float4*)bias)[lane];
    acc.x += b4.x; acc.y += b4.y; acc.z += b4.z; acc.w += b4.w;
    ((float4*)out)[(size_t)r * 64 + lane] = acc;
}

extern "C" void kernel_launch(void* const* d_in, const int* in_sizes, int n_in,
                              void* d_out, int out_size, void* d_ws, size_t ws_size,
                              hipStream_t stream) {
    const float* X    = (const float*)d_in[0];
    const int*   row  = (const int*)d_in[1];
    const int*   col  = (const int*)d_in[2];
    const float* val  = (const float*)d_in[3];
    const float* W    = (const float*)d_in[4];
    const float* bias = (const float*)d_in[5];
    float* out = (float*)d_out;

    // workspace layout (~62 MB)
    char* ws = (char*)d_ws;
    u16* S      = (u16*)ws;                         // 51,200,000 B
    int* starts = (int*)(ws + 51200000);            //   400,064 B (N+1, padded)
    int* cnt    = (int*)(ws + 51600064);            //   400,000 B
    int* perm   = (int*)(ws + 52000064);            // 12,800,000 B
    u16* Wf     = (u16*)(ws + 64800064);            //   131,072 B (16B aligned)
    int* bsum   = (int*)(ws + 64931136);            //     2,048 B
    int* boff   = (int*)(ws + 64933184);            //     2,048 B

    // 1) W -> bf16 B-fragment layout; support = X @ W (MFMA, bf16 store)
    wshuffle_kernel<<<32, 256, 0, stream>>>(W, Wf);
    gemm_mfma_kernel<<<(N_TILES + 3) / 4, 256, 0, stream>>>(X, Wf, S);

    // 2) CSR build: histogram -> hierarchical scan -> placement
    zero_kernel<<<NBLK, 256, 0, stream>>>(cnt, N_NODES);
    hist_kernel<<<N_EDGES / 256, 256, 0, stream>>>(row, cnt);
    blocksum_kernel<<<NBLK, 256, 0, stream>>>(cnt, bsum);
    bscan_kernel<<<1, 512, 0, stream>>>(bsum, boff, starts);
    localscan_kernel<<<NBLK, 256, 0, stream>>>(cnt, boff, starts);
    place_kernel<<<N_EDGES / 256, 256, 0, stream>>>(row, cnt, perm);

    // 3) segmented reduce, single write per output element
    reduce_kernel<<<N_NODES / 4, 256, 0, stream>>>(S, starts, perm, col, val, bias, out);
}

// Round 4
// 803.709 us; speedup vs baseline: 13.8727x; 1.2887x over previous
//
#include <hip/hip_runtime.h>

#define N_NODES 100000
#define N_EDGES 3200000
#define D 256
#define NBLK ((N_NODES + 255) / 256)     // 391 scan blocks
#define GEMM_TILES (N_NODES / 32)        // 3125 tiles of 32 rows
#define GEMM_BLOCKS ((GEMM_TILES + 3) / 4)  // 782
#define HIST_BLOCKS (N_EDGES / 256)      // 12500
#define ZERO_BLOCKS NBLK                 // 391
#define WSH_BLOCKS 32

using u16 = unsigned short;
using u32 = unsigned int;

typedef __attribute__((ext_vector_type(8))) short bf16x8;
typedef __attribute__((ext_vector_type(4))) float f32x4;

__device__ inline u16 f2bf(float f) {
    u32 x = __builtin_bit_cast(u32, f);
    return (u16)((x + 0x7FFFu + ((x >> 16) & 1u)) >> 16);
}
__device__ inline float bf2f(u16 u) {
    return __builtin_bit_cast(float, (u32)u << 16);
}

// -------- prep: zero cnt (blocks 0..390) + W shuffle (blocks 391..422) -----
// Wf layout [kt(8)][nt(16)][lane(64)][j(8)]:
//   b[j] = W[kt*32 + (lane>>4)*8 + j][nt*16 + (lane&15)]
__global__ __launch_bounds__(256) void prep_kernel(
    const float* __restrict__ W, u16* __restrict__ Wf, int* __restrict__ cnt)
{
    if (blockIdx.x < ZERO_BLOCKS) {
        const int i = blockIdx.x * 256 + threadIdx.x;
        if (i < N_NODES) cnt[i] = 0;
        return;
    }
    const int t = (blockIdx.x - ZERO_BLOCKS) * 256 + threadIdx.x;  // 0..8191
    const int kt = t >> 10;
    const int nt = (t >> 6) & 15;
    const int lane = t & 63;
    const int kbase = kt * 32 + ((lane >> 4) * 8);
    const int n = nt * 16 + (lane & 15);
    u16 frag[8];
    #pragma unroll
    for (int j = 0; j < 8; ++j)
        frag[j] = f2bf(W[(size_t)(kbase + j) * D + n]);
    #pragma unroll
    for (int j = 0; j < 8; ++j)
        Wf[(size_t)t * 8 + j] = frag[j];
}

// -------- fused: GEMM (blocks < GEMM_BLOCKS) + histogram (rest) ------------
// GEMM: one wave per 32-row tile, 2 row-halves x 16 col-tiles of 16x16x32.
__global__ __launch_bounds__(256) void gemm_hist_kernel(
    const float* __restrict__ X, const u16* __restrict__ Wf,
    u16* __restrict__ S, const int* __restrict__ row, int* __restrict__ cnt)
{
    if (blockIdx.x >= GEMM_BLOCKS) {
        const int e = (blockIdx.x - GEMM_BLOCKS) * 256 + threadIdx.x;
        atomicAdd(&cnt[row[e]], 1);
        return;
    }
    const int lane = threadIdx.x & 63;
    const int tile = blockIdx.x * 4 + (threadIdx.x >> 6);
    if (tile >= GEMM_TILES) return;
    const int row0 = tile * 32;
    const int m = lane & 15;
    const int quad = lane >> 4;

    f32x4 acc0[16], acc1[16];
    #pragma unroll
    for (int t = 0; t < 16; ++t) {
        acc0[t] = (f32x4){0.f, 0.f, 0.f, 0.f};
        acc1[t] = (f32x4){0.f, 0.f, 0.f, 0.f};
    }

    const float* xA = X + (size_t)(row0 + m) * D + quad * 8;
    const float* xB = X + (size_t)(row0 + 16 + m) * D + quad * 8;
    const bf16x8* __restrict__ Bf = (const bf16x8*)Wf;

    for (int k0 = 0; k0 < 8; ++k0) {               // K-step = 32
        const float4 a0l = *(const float4*)(xA + k0 * 32);
        const float4 a0h = *(const float4*)(xA + k0 * 32 + 4);
        const float4 a1l = *(const float4*)(xB + k0 * 32);
        const float4 a1h = *(const float4*)(xB + k0 * 32 + 4);
        bf16x8 a0, a1;
        a0[0] = (short)f2bf(a0l.x); a0[1] = (short)f2bf(a0l.y);
        a0[2] = (short)f2bf(a0l.z); a0[3] = (short)f2bf(a0l.w);
        a0[4] = (short)f2bf(a0h.x); a0[5] = (short)f2bf(a0h.y);
        a0[6] = (short)f2bf(a0h.z); a0[7] = (short)f2bf(a0h.w);
        a1[0] = (short)f2bf(a1l.x); a1[1] = (short)f2bf(a1l.y);
        a1[2] = (short)f2bf(a1l.z); a1[3] = (short)f2bf(a1l.w);
        a1[4] = (short)f2bf(a1h.x); a1[5] = (short)f2bf(a1h.y);
        a1[6] = (short)f2bf(a1h.z); a1[7] = (short)f2bf(a1h.w);

        const bf16x8* bp = Bf + (size_t)k0 * 1024 + lane;
        #pragma unroll
        for (int g = 0; g < 4; ++g) {              // 4 col-tiles per group
            const bf16x8 b0 = bp[g * 256 + 0];
            const bf16x8 b1 = bp[g * 256 + 64];
            const bf16x8 b2 = bp[g * 256 + 128];
            const bf16x8 b3 = bp[g * 256 + 192];
            acc0[g*4+0] = __builtin_amdgcn_mfma_f32_16x16x32_bf16(a0, b0, acc0[g*4+0], 0, 0, 0);
            acc1[g*4+0] = __builtin_amdgcn_mfma_f32_16x16x32_bf16(a1, b0, acc1[g*4+0], 0, 0, 0);
            acc0[g*4+1] = __builtin_amdgcn_mfma_f32_16x16x32_bf16(a0, b1, acc0[g*4+1], 0, 0, 0);
            acc1[g*4+1] = __builtin_amdgcn_mfma_f32_16x16x32_bf16(a1, b1, acc1[g*4+1], 0, 0, 0);
            acc0[g*4+2] = __builtin_amdgcn_mfma_f32_16x16x32_bf16(a0, b2, acc0[g*4+2], 0, 0, 0);
            acc1[g*4+2] = __builtin_amdgcn_mfma_f32_16x16x32_bf16(a1, b2, acc1[g*4+2], 0, 0, 0);
            acc0[g*4+3] = __builtin_amdgcn_mfma_f32_16x16x32_bf16(a0, b3, acc0[g*4+3], 0, 0, 0);
            acc1[g*4+3] = __builtin_amdgcn_mfma_f32_16x16x32_bf16(a1, b3, acc1[g*4+3], 0, 0, 0);
        }
    }

    // C/D: col = nt*16 + m, row = quad*4 + i  (+16 for second half)
    #pragma unroll
    for (int nt = 0; nt < 16; ++nt) {
        #pragma unroll
        for (int i = 0; i < 4; ++i) {
            S[(size_t)(row0 + quad * 4 + i) * D + nt * 16 + m]      = f2bf(acc0[nt][i]);
            S[(size_t)(row0 + 16 + quad * 4 + i) * D + nt * 16 + m] = f2bf(acc1[nt][i]);
        }
    }
}

// -------- hierarchical scan ------------------------------------------------
__global__ __launch_bounds__(256) void blocksum_kernel(
    const int* __restrict__ cnt, int* __restrict__ bsum)
{
    __shared__ int sh[4];
    const int i = blockIdx.x * 256 + threadIdx.x;
    int x = (i < N_NODES) ? cnt[i] : 0;
    #pragma unroll
    for (int off = 32; off > 0; off >>= 1) x += __shfl_xor(x, off);
    if ((threadIdx.x & 63) == 0) sh[threadIdx.x >> 6] = x;
    __syncthreads();
    if (threadIdx.x == 0) bsum[blockIdx.x] = sh[0] + sh[1] + sh[2] + sh[3];
}

__global__ __launch_bounds__(512) void bscan_kernel(
    const int* __restrict__ bsum, int* __restrict__ boff, int* __restrict__ starts)
{
    __shared__ int wsum[8];
    const int tid = threadIdx.x, lane = tid & 63, wv = tid >> 6;
    const int c = (tid < NBLK) ? bsum[tid] : 0;
    int x = c;
    #pragma unroll
    for (int off = 1; off < 64; off <<= 1) {
        int y = __shfl_up(x, off);
        if (lane >= off) x += y;
    }
    if (lane == 63) wsum[wv] = x;
    __syncthreads();
    if (tid == 0) {
        int run = 0;
        #pragma unroll
        for (int w = 0; w < 8; ++w) { int t = wsum[w]; wsum[w] = run; run += t; }
        starts[N_NODES] = N_EDGES;
    }
    __syncthreads();
    if (tid < NBLK) boff[tid] = x - c + wsum[wv];
}

__global__ __launch_bounds__(256) void localscan_kernel(
    int* __restrict__ cnt, const int* __restrict__ boff, int* __restrict__ starts)
{
    __shared__ int wsum[4];
    const int tid = threadIdx.x, lane = tid & 63, wv = tid >> 6;
    const int i = blockIdx.x * 256 + tid;
    const int c = (i < N_NODES) ? cnt[i] : 0;
    int x = c;
    #pragma unroll
    for (int off = 1; off < 64; off <<= 1) {
        int y = __shfl_up(x, off);
        if (lane >= off) x += y;
    }
    if (lane == 63) wsum[wv] = x;
    __syncthreads();
    if (tid == 0) {
        int run = 0;
        #pragma unroll
        for (int w = 0; w < 4; ++w) { int t = wsum[w]; wsum[w] = run; run += t; }
    }
    __syncthreads();
    const int excl = x - c + wsum[wv] + boff[blockIdx.x];
    if (i < N_NODES) { starts[i] = excl; cnt[i] = excl; }
}

// -------- placement: write packed {col,val} pairs grouped by row -----------
__global__ __launch_bounds__(256) void place_kernel(
    const int* __restrict__ row, const int* __restrict__ col,
    const float* __restrict__ val, int* __restrict__ cursor,
    uint2* __restrict__ pce)
{
    const int e = blockIdx.x * 256 + threadIdx.x;
    const int r = row[e];
    const int c = col[e];
    const float v = val[e];
    const int pos = atomicAdd(&cursor[r], 1);
    pce[pos] = make_uint2((u32)c, __builtin_bit_cast(u32, v));
}

// -------- segmented reduce: one wave/row, coalesced pairs, 8-deep MLP ------
__global__ __launch_bounds__(256) void reduce_kernel(
    const u16* __restrict__ S, const int* __restrict__ starts,
    const uint2* __restrict__ pce, const float* __restrict__ bias,
    float* __restrict__ out)
{
    const int lane = threadIdx.x & 63;
    const int r = blockIdx.x * 4 + (threadIdx.x >> 6);
    const int s0 = starts[r];
    const int s1 = starts[r + 1];

    const ushort4* __restrict__ S4 = (const ushort4*)S;
    float4 acc = make_float4(0.f, 0.f, 0.f, 0.f);

    for (int base = s0; base < s1; base += 64) {
        const int n = min(64, s1 - base);
        uint2 pr = make_uint2(0u, 0u);
        if (lane < n) pr = pce[base + lane];
        const int c = (int)pr.x;
        const float v = __builtin_bit_cast(float, pr.y);

        int i = 0;
        for (; i + 8 <= n; i += 8) {
            int cc[8]; float vv[8]; ushort4 s[8];
            #pragma unroll
            for (int u = 0; u < 8; ++u) {
                cc[u] = __shfl(c, i + u);
                vv[u] = __shfl(v, i + u);
            }
            #pragma unroll
            for (int u = 0; u < 8; ++u)
                s[u] = S4[(size_t)cc[u] * 64 + lane];
            #pragma unroll
            for (int u = 0; u < 8; ++u) {
                acc.x += vv[u] * bf2f(s[u].x);
                acc.y += vv[u] * bf2f(s[u].y);
                acc.z += vv[u] * bf2f(s[u].z);
                acc.w += vv[u] * bf2f(s[u].w);
            }
        }
        for (; i < n; ++i) {
            const int c0 = __shfl(c, i);
            const float v0 = __shfl(v, i);
            const ushort4 a0 = S4[(size_t)c0 * 64 + lane];
            acc.x += v0 * bf2f(a0.x);
            acc.y += v0 * bf2f(a0.y);
            acc.z += v0 * bf2f(a0.z);
            acc.w += v0 * bf2f(a0.w);
        }
    }

    const float4 b4 = ((const float4*)bias)[lane];
    acc.x += b4.x; acc.y += b4.y; acc.z += b4.z; acc.w += b4.w;
    ((float4*)out)[(size_t)r * 64 + lane] = acc;
}

extern "C" void kernel_launch(void* const* d_in, const int* in_sizes, int n_in,
                              void* d_out, int out_size, void* d_ws, size_t ws_size,
                              hipStream_t stream) {
    const float* X    = (const float*)d_in[0];
    const int*   row  = (const int*)d_in[1];
    const int*   col  = (const int*)d_in[2];
    const float* val  = (const float*)d_in[3];
    const float* W    = (const float*)d_in[4];
    const float* bias = (const float*)d_in[5];
    float* out = (float*)d_out;

    // workspace layout (~77.7 MB; >=102.4 MB proven available in round 1)
    char* ws = (char*)d_ws;
    u16*   Sx     = (u16*)ws;                       // 51,200,000 B
    int*   starts = (int*)(ws + 51200000);          //    400,064 B (N+1, padded)
    int*   cnt    = (int*)(ws + 51600064);          //    400,000 B
    uint2* pce    = (uint2*)(ws + 52000064);        // 25,600,000 B (8-aligned)
    u16*   Wf     = (u16*)(ws + 77600064);          //    131,072 B (16-aligned)
    int*   bsum   = (int*)(ws + 77731136);          //      2,048 B
    int*   boff   = (int*)(ws + 77733184);          //      2,048 B

    // 1) prep: zero cnt + W -> bf16 B-fragment layout
    prep_kernel<<<ZERO_BLOCKS + WSH_BLOCKS, 256, 0, stream>>>(W, Wf, cnt);

    // 2) fused GEMM + histogram
    gemm_hist_kernel<<<GEMM_BLOCKS + HIST_BLOCKS, 256, 0, stream>>>(X, Wf, Sx, row, cnt);

    // 3) scan
    blocksum_kernel<<<NBLK, 256, 0, stream>>>(cnt, bsum);
    bscan_kernel<<<1, 512, 0, stream>>>(bsum, boff, starts);
    localscan_kernel<<<NBLK, 256, 0, stream>>>(cnt, boff, starts);

    // 4) placement (packed col/val pairs)
    place_kernel<<<N_EDGES / 256, 256, 0, stream>>>(row, col, val, cnt, pce);

    // 5) segmented reduce
    reduce_kernel<<<N_NODES / 4, 256, 0, stream>>>(Sx, starts, pce, bias, out);
}